// Round 7
// baseline (3071.082 us; speedup 1.0000x reference)
//
#include <hip/hip_runtime.h>
#include <hip/hip_bf16.h>

// LSTM decoder: L=2, B=64, T=512, H=IN=512, gates G=2048 (i,f,g,o).
// Round 7: decoupled per-layer dataflow sync (no global barrier).
//  - h0 gets a 4-deep ring; layer-0 runs up to 3 phases ahead of layer-1
//    (back-pressure via layer-1 flags). Layer-1 chain no longer couples to
//    layer-0's stalls and vice versa.
//  - per-block phase FLAGS (plain coherent dword stores, no atomic RMW);
//    wave-parallel poll: lane l loads flag[l] (one coalesced 256B sc-load)
//    + __all ballot -> one MALL round trip per poll iteration.
//  - everything else (W LDS image, MFMA structure, coherent h exchange,
//    numerics: ih single bf16, hh hi+lo W x hi+lo h) = round-6 proven.

#define TT 512

using short8 = __attribute__((ext_vector_type(8))) short;
using f32x4  = __attribute__((ext_vector_type(4))) float;

__device__ __forceinline__ short f2bf(float f) {
  unsigned u = __float_as_uint(f);
  u = (u + 0x7fffu + ((u >> 16) & 1u)) >> 16;  // RNE
  return (short)u;
}
__device__ __forceinline__ float bf2f(short s) {
  return __uint_as_float(((unsigned)(unsigned short)s) << 16);
}
__device__ __forceinline__ float sigf(float x) { return 1.f / (1.f + __expf(-x)); }
__device__ __forceinline__ float tanh_(float x) { return 1.f - 2.f / (__expf(2.f * x) + 1.f); }

// 8 coherent 16B loads, NO wait (caller ties the waitcnt to the results).
__device__ __forceinline__ void ld8_nw(short8* d,
    const short* p0, const short* p1, const short* p2, const short* p3,
    const short* p4, const short* p5, const short* p6, const short* p7) {
  asm volatile(
      "global_load_dwordx4 %0, %8, off sc0 sc1\n\t"
      "global_load_dwordx4 %1, %9, off sc0 sc1\n\t"
      "global_load_dwordx4 %2, %10, off sc0 sc1\n\t"
      "global_load_dwordx4 %3, %11, off sc0 sc1\n\t"
      "global_load_dwordx4 %4, %12, off sc0 sc1\n\t"
      "global_load_dwordx4 %5, %13, off sc0 sc1\n\t"
      "global_load_dwordx4 %6, %14, off sc0 sc1\n\t"
      "global_load_dwordx4 %7, %15, off sc0 sc1"
      : "=&v"(d[0]), "=&v"(d[1]), "=&v"(d[2]), "=&v"(d[3]),
        "=&v"(d[4]), "=&v"(d[5]), "=&v"(d[6]), "=&v"(d[7])
      : "v"(p0), "v"(p1), "v"(p2), "v"(p3),
        "v"(p4), "v"(p5), "v"(p6), "v"(p7)
      : "memory");
}

#define TIE8(A, CNT)                                                        \
  asm volatile(CNT : "+v"(A[0]), "+v"(A[1]), "+v"(A[2]), "+v"(A[3]),        \
                     "+v"(A[4]), "+v"(A[5]), "+v"(A[6]), "+v"(A[7])         \
               ::"memory")

__device__ __forceinline__ void stc_short(short* p, short v) {
  asm volatile("global_store_short %0, %1, off sc0 sc1"
               :: "v"(p), "v"((int)v) : "memory");
}
__device__ __forceinline__ void stc_int(int* p, int v) {
  asm volatile("global_store_dword %0, %1, off sc0 sc1"
               :: "v"(p), "v"(v) : "memory");
}

// wave-parallel poll: lanes 0..63 each watch one block's flag of each layer.
// Exits when all fl0[l] >= t0 AND all fl1[l] >= t1. Wave-0 only + barrier.
__device__ __forceinline__ void pollwait(const int* f0p, const int* f1p,
                                         int t0, int t1, int tid) {
  if (tid < 64) {
    int f0, f1;
    for (;;) {
      asm volatile(
          "global_load_dword %0, %2, off sc0 sc1\n\t"
          "global_load_dword %1, %3, off sc0 sc1\n\t"
          "s_waitcnt vmcnt(0)"
          : "=&v"(f0), "=&v"(f1)
          : "v"(f0p), "v"(f1p)
          : "memory");
      if (__all(f0 >= t0 && f1 >= t1)) break;
      __builtin_amdgcn_s_sleep(1);
    }
  }
  __syncthreads();
}

// ---- x fp32 [64][512][512] -> bf16 in first half of each out row ----
__global__ __launch_bounds__(256) void conv_x(const float* __restrict__ x,
                                              short* __restrict__ xo) {
  size_t g = (size_t)blockIdx.x * 256 + threadIdx.x;  // 2,097,152
  size_t i = g * 8;
  float4 v0 = *(const float4*)(x + i);
  float4 v1 = *(const float4*)(x + i + 4);
  short8 r;
  r[0] = f2bf(v0.x); r[1] = f2bf(v0.y); r[2] = f2bf(v0.z); r[3] = f2bf(v0.w);
  r[4] = f2bf(v1.x); r[5] = f2bf(v1.y); r[6] = f2bf(v1.z); r[7] = f2bf(v1.w);
  *(short8*)(xo + (i >> 9) * 1024 + (i & 511)) = r;
}

// ---- W pack: per-block contiguous LDS image (49152 shorts per (l,j8)) ----
__global__ __launch_bounds__(256) void conv_w(const float* __restrict__ Wih,
                                              const float* __restrict__ Whh,
                                              short* __restrict__ wp) {
  int g = blockIdx.x * 256 + threadIdx.x;  // 0..786431
  int l = g / 393216;
  int rem = g % 393216;
  int j8 = rem / 6144;
  int q8 = rem % 6144;
  int s, hl, bt, c, lane;
  if (q8 < 2048) {
    s = 0; hl = 0;
    int seg = q8 >> 6; bt = seg >> 4; c = seg & 15; lane = q8 & 63;
  } else {
    int q = q8 - 2048;
    s = 1;
    int seg = q >> 6; bt = seg >> 5; c = (seg >> 1) & 15; hl = seg & 1;
    lane = q & 63;
  }
  int r = lane & 15;
  int gg = r >> 2, jj = r & 3;
  int R = gg * 512 + j8 * 8 + bt * 4 + jj;
  int k = c * 32 + (lane >> 4) * 8;
  const float* src = (s ? Whh : Wih) + ((size_t)(l * 2048 + R)) * 512 + k;
  short8 o;
#pragma unroll
  for (int e = 0; e < 8; ++e) {
    float v = src[e];
    short hi = f2bf(v);
    o[e] = hl ? f2bf(v - bf2f(hi)) : hi;
  }
  *(short8*)(wp + (size_t)g * 8) = o;
}

// ---- init: h0(-1) -> ring slot 3; h1(-1) -> slot 1; flags = 0 ----
__global__ __launch_bounds__(256) void init_state(const float* __restrict__ h0,
                                                  short* __restrict__ h0hi,
                                                  short* __restrict__ h0lo,
                                                  short* __restrict__ h1hi,
                                                  short* __restrict__ h1lo,
                                                  int* __restrict__ flags) {
  int i = blockIdx.x * 256 + threadIdx.x;  // 0..65535 [l][b][j]
  int l = i >> 15, bj = i & 32767;
  int b = bj >> 9, j = bj & 511;
  float h = h0[i];
  short hi = f2bf(h);
  int o = (j >> 3) * 512 + b * 8 + (j & 7);
  if (l == 0) {
    h0hi[3 * 32768 + o] = hi;
    h0lo[3 * 32768 + o] = f2bf(h - bf2f(hi));
  } else {
    h1hi[1 * 32768 + o] = hi;
    h1lo[1 * 32768 + o] = f2bf(h - bf2f(hi));
  }
  if (blockIdx.x == 0 && threadIdx.x < 128) flags[threadIdx.x] = 0;
}

// ---- persistent LSTM ----------------------------------------------------
// grid 128 = [layer(2)][j8(64)]; block 512 = 8 waves (kq = wv&3, ah = wv>>2).
// dyn LDS 132096B: [0,98304) W image; [98304,..) float sG[4][32][66].
__global__ __launch_bounds__(512, 1) void lstm_persist(
    const short* __restrict__ wp, const float* __restrict__ c0,
    const float* __restrict__ bih, const float* __restrict__ bhh,
    short* __restrict__ h0hi, short* __restrict__ h0lo,
    short* __restrict__ h1hi, short* __restrict__ h1lo,
    int* __restrict__ flags, float* __restrict__ out) {
  extern __shared__ char smem[];
  short* lw = (short*)smem;             // 49152 shorts
  float* sG = (float*)(smem + 98304);   // [kq][s][b] stride 66

  const int tid = threadIdx.x;
  const int layer = blockIdx.x >> 6;
  const int j8 = blockIdx.x & 63;
  const int wv = tid >> 6;
  const int kq = wv & 3;
  const int ah = wv >> 2;
  const int lane = tid & 63;
  const int m = lane & 15;
  const int koq = lane >> 4;
  const int cbase = kq << 2;

  {  // W slice -> LDS (one-time)
    const short* src = wp + (size_t)(layer * 64 + j8) * 49152;
    for (int i = tid; i < 6144; i += 512)
      *(short8*)(lw + i * 8) = *(const short8*)(src + i * 8);
  }

  const int sb = tid >> 3, sj = tid & 7;
  const int j = (j8 << 3) + sj;
  float creg = c0[layer * 32768 + sb * 512 + j];
  float hf = 0.f;
  float bsum[4];
#pragma unroll
  for (int g = 0; g < 4; ++g)
    bsum[g] = bih[layer * 2048 + g * 512 + j] + bhh[layer * 2048 + g * 512 + j];
  __syncthreads();

  const int br0 = ((ah * 2 + 0) << 4) + m;
  const int br1 = ((ah * 2 + 1) << 4) + m;
  const short* xo = (const short*)out;
  const int* f0p = flags + lane;        // layer-0 flags
  const int* f1p = flags + 64 + lane;   // layer-1 flags

  f32x4 acc[2][2];

#define ZACC()                                                   \
  {                                                              \
    _Pragma("unroll") for (int u = 0; u < 2; ++u)                \
        _Pragma("unroll") for (int v = 0; v < 2; ++v)            \
            acc[u][v] = f32x4{0.f, 0.f, 0.f, 0.f};               \
  }

#define PA(rX, cc, br) \
  ((rX) + ((((cbase + (cc)) << 2) + koq) << 9) + (br) * 8)

  // hh: hi+lo W x hi+lo h (3 MFMA per term), Ah/Al in regs
#define HH_MFMA(Ah, Al)                                                        \
  _Pragma("unroll") for (int cc = 0; cc < 4; ++cc) {                           \
    const int c = cbase + cc;                                                  \
    short8 bh0 = *(const short8*)(lw + 16384 + (c * 2 + 0) * 512 + lane * 8);  \
    short8 bl0 = *(const short8*)(lw + 16384 + (c * 2 + 1) * 512 + lane * 8);  \
    short8 bh1 = *(const short8*)(lw + 16384 + ((16 + c) * 2 + 0) * 512 + lane * 8); \
    short8 bl1 = *(const short8*)(lw + 16384 + ((16 + c) * 2 + 1) * 512 + lane * 8); \
    _Pragma("unroll") for (int it = 0; it < 2; ++it) {                         \
      short8 a = Ah[cc * 2 + it];                                              \
      short8 al = Al[cc * 2 + it];                                             \
      acc[0][it] = __builtin_amdgcn_mfma_f32_16x16x32_bf16(a, bh0, acc[0][it], 0, 0, 0); \
      acc[0][it] = __builtin_amdgcn_mfma_f32_16x16x32_bf16(a, bl0, acc[0][it], 0, 0, 0); \
      acc[0][it] = __builtin_amdgcn_mfma_f32_16x16x32_bf16(al, bh0, acc[0][it], 0, 0, 0); \
      acc[1][it] = __builtin_amdgcn_mfma_f32_16x16x32_bf16(a, bh1, acc[1][it], 0, 0, 0); \
      acc[1][it] = __builtin_amdgcn_mfma_f32_16x16x32_bf16(a, bl1, acc[1][it], 0, 0, 0); \
      acc[1][it] = __builtin_amdgcn_mfma_f32_16x16x32_bf16(al, bh1, acc[1][it], 0, 0, 0); \
    }                                                                          \
  }

  // sG exchange + reduce + gates; yields cn/hn for this thread's (sb, j)
#define EPILOGUE(CN, HN)                                                       \
  _Pragma("unroll") for (int bt = 0; bt < 2; ++bt)                             \
      _Pragma("unroll") for (int it = 0; it < 2; ++it) {                       \
    const int srow = bt * 16 + m;                                              \
    const int col = ((ah * 2 + it) << 4) + (koq << 2);                         \
    _Pragma("unroll") for (int r = 0; r < 4; ++r)                              \
        sG[(kq * 32 + srow) * 66 + col + r] = acc[bt][it][r];                  \
  }                                                                            \
  __syncthreads();                                                             \
  float CN, HN;                                                                \
  {                                                                            \
    const int bt = sj >> 2, jl = sj & 3;                                       \
    float gv[4];                                                               \
    _Pragma("unroll") for (int g = 0; g < 4; ++g) {                            \
      const int s = bt * 16 + g * 4 + jl;                                      \
      gv[g] = sG[(0 * 32 + s) * 66 + sb] + sG[(1 * 32 + s) * 66 + sb] +        \
              sG[(2 * 32 + s) * 66 + sb] + sG[(3 * 32 + s) * 66 + sb] +        \
              bsum[g];                                                         \
    }                                                                          \
    CN = sigf(gv[1]) * creg + sigf(gv[0]) * tanh_(gv[2]);                      \
    HN = sigf(gv[3]) * tanh_(CN);                                              \
  }

  if (layer == 0) {
    // ---- LAYER 0: own 64-block flag chain, h0 ring depth 4 ----
    // prologue: ih(0)
    ZACC();
#pragma unroll
    for (int cc = 0; cc < 4; ++cc) {
      const int c = cbase + cc;
      const int k = c * 32 + (koq << 3);
      short8 b0 = *(const short8*)(lw + c * 512 + lane * 8);
      short8 b1 = *(const short8*)(lw + (16 + c) * 512 + lane * 8);
#pragma unroll
      for (int it = 0; it < 2; ++it) {
        const int br = it ? br1 : br0;
        short8 a = *(const short8*)(xo + ((size_t)br * TT + 0) * 1024 + k);
        acc[0][it] = __builtin_amdgcn_mfma_f32_16x16x32_bf16(a, b0, acc[0][it], 0, 0, 0);
        acc[1][it] = __builtin_amdgcn_mfma_f32_16x16x32_bf16(a, b1, acc[1][it], 0, 0, 0);
      }
    }

    for (int p = 0; p < TT; ++p) {
      // need: own layer at p (h0(p-1) ready); ring guard: layer-1 done p-3
      pollwait(f0p, f1p, p, p - 3, tid);

      short8 Ah[8], Al[8];
      const short* rh = h0hi + ((p - 1) & 3) * 32768;
      const short* rl = h0lo + ((p - 1) & 3) * 32768;
      ld8_nw(Ah, PA(rh, 0, br0), PA(rh, 0, br1), PA(rh, 1, br0), PA(rh, 1, br1),
                 PA(rh, 2, br0), PA(rh, 2, br1), PA(rh, 3, br0), PA(rh, 3, br1));
      ld8_nw(Al, PA(rl, 0, br0), PA(rl, 0, br1), PA(rl, 1, br0), PA(rl, 1, br1),
                 PA(rl, 2, br0), PA(rl, 2, br1), PA(rl, 3, br0), PA(rl, 3, br1));
      TIE8(Ah, "s_waitcnt vmcnt(0)");
      TIE8(Al, "");
      HH_MFMA(Ah, Al);

      EPILOGUE(cn, hn);
      creg = cn;
      hf = hn;
      {  // h0(p) -> ring slot p&3
        short* dh = h0hi + (p & 3) * 32768 + (j8 << 9) + tid;
        short* dl = h0lo + (p & 3) * 32768 + (j8 << 9) + tid;
        const short hb = f2bf(hn);
        stc_short(dh, hb);
        stc_short(dl, f2bf(hn - bf2f(hb)));
      }
      __syncthreads();  // drain all waves' h stores
      if (tid == 0) stc_int(flags + j8, p + 1);

      if (p + 1 < TT) {  // ih(p+1) while peers catch up
        ZACC();
#pragma unroll
        for (int cc = 0; cc < 4; ++cc) {
          const int c = cbase + cc;
          const int k = c * 32 + (koq << 3);
          short8 b0 = *(const short8*)(lw + c * 512 + lane * 8);
          short8 b1 = *(const short8*)(lw + (16 + c) * 512 + lane * 8);
#pragma unroll
          for (int it = 0; it < 2; ++it) {
            const int br = it ? br1 : br0;
            short8 a = *(const short8*)(xo + ((size_t)br * TT + p + 1) * 1024 + k);
            acc[0][it] = __builtin_amdgcn_mfma_f32_16x16x32_bf16(a, b0, acc[0][it], 0, 0, 0);
            acc[1][it] = __builtin_amdgcn_mfma_f32_16x16x32_bf16(a, b1, acc[1][it], 0, 0, 0);
          }
        }
      }
    }
  } else {
    // ---- LAYER 1: consumes h0 ring, own h1 parity chain ----
    for (int tau = 1; tau <= TT; ++tau) {
      const int tl = tau - 1;
      // need: h0(tau-1) ready (fl0 >= tau); own h1(tau-2) ready (fl1 >= tau-1)
      pollwait(f0p, f1p, tau, tau - 1, tid);

      ZACC();
      short8 Ax[8], Ah[8], Al[8];
      const short* ph = h0hi + (tl & 3) * 32768;            // h0(tau-1)
      const short* rh = h1hi + (tau & 1) * 32768;           // h1(tau-2)
      const short* rl = h1lo + (tau & 1) * 32768;
      ld8_nw(Ax, PA(ph, 0, br0), PA(ph, 0, br1), PA(ph, 1, br0), PA(ph, 1, br1),
                 PA(ph, 2, br0), PA(ph, 2, br1), PA(ph, 3, br0), PA(ph, 3, br1));
      ld8_nw(Ah, PA(rh, 0, br0), PA(rh, 0, br1), PA(rh, 1, br0), PA(rh, 1, br1),
                 PA(rh, 2, br0), PA(rh, 2, br1), PA(rh, 3, br0), PA(rh, 3, br1));
      ld8_nw(Al, PA(rl, 0, br0), PA(rl, 0, br1), PA(rl, 1, br0), PA(rl, 1, br1),
                 PA(rl, 2, br0), PA(rl, 2, br1), PA(rl, 3, br0), PA(rl, 3, br1));
      TIE8(Ax, "s_waitcnt vmcnt(16)");  // Ax done; Ah/Al still in flight
#pragma unroll
      for (int cc = 0; cc < 4; ++cc) {
        const int c = cbase + cc;
        short8 b0 = *(const short8*)(lw + c * 512 + lane * 8);
        short8 b1 = *(const short8*)(lw + (16 + c) * 512 + lane * 8);
#pragma unroll
        for (int it = 0; it < 2; ++it) {
          short8 a = Ax[cc * 2 + it];
          acc[0][it] = __builtin_amdgcn_mfma_f32_16x16x32_bf16(a, b0, acc[0][it], 0, 0, 0);
          acc[1][it] = __builtin_amdgcn_mfma_f32_16x16x32_bf16(a, b1, acc[1][it], 0, 0, 0);
        }
      }
      TIE8(Ah, "s_waitcnt vmcnt(0)");
      TIE8(Al, "");
      HH_MFMA(Ah, Al);

      EPILOGUE(cn, hn);
      creg = cn;
      hf = hn;
      {  // h1(tau-1) -> slot (tau+1)&1
        short* dh = h1hi + ((tau + 1) & 1) * 32768 + (j8 << 9) + tid;
        short* dl = h1lo + ((tau + 1) & 1) * 32768 + (j8 << 9) + tid;
        const short hb = f2bf(hn);
        stc_short(dh, hb);
        stc_short(dl, f2bf(hn - bf2f(hb)));
      }
      __syncthreads();  // drain
      if (tid == 0) stc_int(flags + 64 + j8, tau);
      // out write AFTER flag (off the critical notification path)
      __builtin_nontemporal_store(hn, &out[((size_t)sb * 512 + tl) * 512 + j]);
    }
  }

  // finals from registers
  out[16777216 + layer * 32768 + sb * 512 + j] = hf;
  out[16777216 + 65536 + layer * 32768 + sb * 512 + j] = creg;
}

// ---- host ---------------------------------------------------------------

extern "C" void kernel_launch(void* const* d_in, const int* in_sizes, int n_in,
                              void* d_out, int out_size, void* d_ws,
                              size_t ws_size, hipStream_t stream) {
  const float* x = (const float*)d_in[0];
  const float* h0 = (const float*)d_in[1];
  const float* c0 = (const float*)d_in[2];
  const float* Wih = (const float*)d_in[3];
  const float* Whh = (const float*)d_in[4];
  const float* bih = (const float*)d_in[5];
  const float* bhh = (const float*)d_in[6];
  float* out = (float*)d_out;

  char* ws = (char*)d_ws;
  short* wp   = (short*)(ws + 0);              // 12 MB fragment-packed W
  short* h0hi = (short*)(ws + 12582912);       // 256 KB: 4-slot ring
  short* h0lo = (short*)(ws + 12845056);       // 256 KB
  short* h1hi = (short*)(ws + 13107200);       // 128 KB: 2-slot parity
  short* h1lo = (short*)(ws + 13238272);       // 128 KB
  int*  flags = (int*)(ws + 13369344);         // 512 B: fl0[64], fl1[64]
  // total ws use: ~12.8 MB (proven budget)

  hipFuncSetAttribute(reinterpret_cast<const void*>(lstm_persist),
                      hipFuncAttributeMaxDynamicSharedMemorySize, 132096);

  conv_x<<<8192, 256, 0, stream>>>(x, (short*)out);
  conv_w<<<3072, 256, 0, stream>>>(Wih, Whh, wp);
  init_state<<<256, 256, 0, stream>>>(h0, h0hi, h0lo, h1hi, h1lo, flags);

  void* args[] = {(void*)&wp,   (void*)&c0,   (void*)&bih,  (void*)&bhh,
                  (void*)&h0hi, (void*)&h0lo, (void*)&h1hi, (void*)&h1lo,
                  (void*)&flags, (void*)&out};
  hipLaunchCooperativeKernel(reinterpret_cast<void*>(lstm_persist), dim3(128),
                             dim3(512), args, 132096, stream);
}

// Round 8
// 2785.390 us; speedup vs baseline: 1.1026x; 1.1026x over previous
//
#include <hip/hip_runtime.h>
#include <hip/hip_bf16.h>

// LSTM decoder: L=2, B=64, T=512, H=IN=512, gates G=2048 (i,f,g,o).
// Round 8: round-7 decoupled per-layer dataflow, sync fabric fixed:
//  - PADDED flags: one 128B MALL line per block (round-7 packed 2 lines ->
//    64-way producer write serialization = the regression). Poll = lane-
//    strided 64-line gather + __all ballot, one RT per iteration.
//  - explicit s_waitcnt vmcnt(0) before drain barrier (asm stores are not
//    tracked by compiler waitcnt insertion).
//  - layer-1 pre-issues the Ax (h0) burst before its own-layer poll, using
//    f0seen (layer-0 min flag sampled during each poll, wave-min + LDS
//    broadcast). Layer-0 runs ahead -> Ax RT fully hidden.
// Numerics (5 rounds stable, absmax 0.0039): ih single bf16, hh hi+lo W x
// hi+lo h, fp32 c/gates. W fragment-packed LDS image per block.

#define TT 512

using short8 = __attribute__((ext_vector_type(8))) short;
using f32x4  = __attribute__((ext_vector_type(4))) float;

__device__ __forceinline__ short f2bf(float f) {
  unsigned u = __float_as_uint(f);
  u = (u + 0x7fffu + ((u >> 16) & 1u)) >> 16;  // RNE
  return (short)u;
}
__device__ __forceinline__ float bf2f(short s) {
  return __uint_as_float(((unsigned)(unsigned short)s) << 16);
}
__device__ __forceinline__ float sigf(float x) { return 1.f / (1.f + __expf(-x)); }
__device__ __forceinline__ float tanh_(float x) { return 1.f - 2.f / (__expf(2.f * x) + 1.f); }

// 8 coherent 16B loads, NO wait (caller ties the waitcnt to the results).
__device__ __forceinline__ void ld8_nw(short8* d,
    const short* p0, const short* p1, const short* p2, const short* p3,
    const short* p4, const short* p5, const short* p6, const short* p7) {
  asm volatile(
      "global_load_dwordx4 %0, %8, off sc0 sc1\n\t"
      "global_load_dwordx4 %1, %9, off sc0 sc1\n\t"
      "global_load_dwordx4 %2, %10, off sc0 sc1\n\t"
      "global_load_dwordx4 %3, %11, off sc0 sc1\n\t"
      "global_load_dwordx4 %4, %12, off sc0 sc1\n\t"
      "global_load_dwordx4 %5, %13, off sc0 sc1\n\t"
      "global_load_dwordx4 %6, %14, off sc0 sc1\n\t"
      "global_load_dwordx4 %7, %15, off sc0 sc1"
      : "=&v"(d[0]), "=&v"(d[1]), "=&v"(d[2]), "=&v"(d[3]),
        "=&v"(d[4]), "=&v"(d[5]), "=&v"(d[6]), "=&v"(d[7])
      : "v"(p0), "v"(p1), "v"(p2), "v"(p3),
        "v"(p4), "v"(p5), "v"(p6), "v"(p7)
      : "memory");
}

#define TIE8(A, CNT)                                                        \
  asm volatile(CNT : "+v"(A[0]), "+v"(A[1]), "+v"(A[2]), "+v"(A[3]),        \
                     "+v"(A[4]), "+v"(A[5]), "+v"(A[6]), "+v"(A[7])         \
               ::"memory")

__device__ __forceinline__ void stc_short(short* p, short v) {
  asm volatile("global_store_short %0, %1, off sc0 sc1"
               :: "v"(p), "v"((int)v) : "memory");
}
__device__ __forceinline__ void stc_int(int* p, int v) {
  asm volatile("global_store_dword %0, %1, off sc0 sc1"
               :: "v"(p), "v"(v) : "memory");
}
__device__ __forceinline__ void drain_vm() {
  asm volatile("s_waitcnt vmcnt(0)" ::: "memory");
}

// one poll iteration: two coherent dword loads + one wait
__device__ __forceinline__ void pollld(int& a, int& b, const int* pa,
                                       const int* pb) {
  asm volatile(
      "global_load_dword %0, %2, off sc0 sc1\n\t"
      "global_load_dword %1, %3, off sc0 sc1\n\t"
      "s_waitcnt vmcnt(0)"
      : "=&v"(a), "=&v"(b) : "v"(pa), "v"(pb) : "memory");
}

__device__ __forceinline__ int wave_min(int v) {
#pragma unroll
  for (int o = 32; o; o >>= 1) v = min(v, __shfl_xor(v, o, 64));
  return v;
}

// ---- x fp32 [64][512][512] -> bf16 in first half of each out row ----
__global__ __launch_bounds__(256) void conv_x(const float* __restrict__ x,
                                              short* __restrict__ xo) {
  size_t g = (size_t)blockIdx.x * 256 + threadIdx.x;  // 2,097,152
  size_t i = g * 8;
  float4 v0 = *(const float4*)(x + i);
  float4 v1 = *(const float4*)(x + i + 4);
  short8 r;
  r[0] = f2bf(v0.x); r[1] = f2bf(v0.y); r[2] = f2bf(v0.z); r[3] = f2bf(v0.w);
  r[4] = f2bf(v1.x); r[5] = f2bf(v1.y); r[6] = f2bf(v1.z); r[7] = f2bf(v1.w);
  *(short8*)(xo + (i >> 9) * 1024 + (i & 511)) = r;
}

// ---- W pack: per-block contiguous LDS image (49152 shorts per (l,j8)) ----
__global__ __launch_bounds__(256) void conv_w(const float* __restrict__ Wih,
                                              const float* __restrict__ Whh,
                                              short* __restrict__ wp) {
  int g = blockIdx.x * 256 + threadIdx.x;  // 0..786431
  int l = g / 393216;
  int rem = g % 393216;
  int j8 = rem / 6144;
  int q8 = rem % 6144;
  int s, hl, bt, c, lane;
  if (q8 < 2048) {
    s = 0; hl = 0;
    int seg = q8 >> 6; bt = seg >> 4; c = seg & 15; lane = q8 & 63;
  } else {
    int q = q8 - 2048;
    s = 1;
    int seg = q >> 6; bt = seg >> 5; c = (seg >> 1) & 15; hl = seg & 1;
    lane = q & 63;
  }
  int r = lane & 15;
  int gg = r >> 2, jj = r & 3;
  int R = gg * 512 + j8 * 8 + bt * 4 + jj;
  int k = c * 32 + (lane >> 4) * 8;
  const float* src = (s ? Whh : Wih) + ((size_t)(l * 2048 + R)) * 512 + k;
  short8 o;
#pragma unroll
  for (int e = 0; e < 8; ++e) {
    float v = src[e];
    short hi = f2bf(v);
    o[e] = hl ? f2bf(v - bf2f(hi)) : hi;
  }
  *(short8*)(wp + (size_t)g * 8) = o;
}

// ---- init: h0(-1) -> ring slot 3; h1(-1) -> slot 1; padded flags = 0 ----
__global__ __launch_bounds__(256) void init_state(const float* __restrict__ h0,
                                                  short* __restrict__ h0hi,
                                                  short* __restrict__ h0lo,
                                                  short* __restrict__ h1hi,
                                                  short* __restrict__ h1lo,
                                                  int* __restrict__ flags) {
  int i = blockIdx.x * 256 + threadIdx.x;  // 0..65535 [l][b][j]
  int l = i >> 15, bj = i & 32767;
  int b = bj >> 9, j = bj & 511;
  float h = h0[i];
  short hi = f2bf(h);
  int o = (j >> 3) * 512 + b * 8 + (j & 7);
  if (l == 0) {
    h0hi[3 * 32768 + o] = hi;
    h0lo[3 * 32768 + o] = f2bf(h - bf2f(hi));
  } else {
    h1hi[1 * 32768 + o] = hi;
    h1lo[1 * 32768 + o] = f2bf(h - bf2f(hi));
  }
  if (blockIdx.x == 0 && threadIdx.x < 128) flags[threadIdx.x * 32] = 0;
}

// ---- persistent LSTM ----------------------------------------------------
// grid 128 = [layer(2)][j8(64)]; block 512 = 8 waves (kq = wv&3, ah = wv>>2).
// dyn LDS 132352B: [0,98304) W; [98304,132096) sG[4][32][66]; [132096) sf0.
__global__ __launch_bounds__(512, 1) void lstm_persist(
    const short* __restrict__ wp, const float* __restrict__ c0,
    const float* __restrict__ bih, const float* __restrict__ bhh,
    short* __restrict__ h0hi, short* __restrict__ h0lo,
    short* __restrict__ h1hi, short* __restrict__ h1lo,
    int* __restrict__ flags, float* __restrict__ out) {
  extern __shared__ char smem[];
  short* lw = (short*)smem;             // 49152 shorts
  float* sG = (float*)(smem + 98304);   // [kq][s][b] stride 66
  int* sf0 = (int*)(smem + 132096);

  const int tid = threadIdx.x;
  const int layer = blockIdx.x >> 6;
  const int j8 = blockIdx.x & 63;
  const int wv = tid >> 6;
  const int kq = wv & 3;
  const int ah = wv >> 2;
  const int lane = tid & 63;
  const int m = lane & 15;
  const int koq = lane >> 4;
  const int cbase = kq << 2;

  {  // W slice -> LDS (one-time)
    const short* src = wp + (size_t)(layer * 64 + j8) * 49152;
    for (int i = tid; i < 6144; i += 512)
      *(short8*)(lw + i * 8) = *(const short8*)(src + i * 8);
  }

  const int sb = tid >> 3, sj = tid & 7;
  const int j = (j8 << 3) + sj;
  float creg = c0[layer * 32768 + sb * 512 + j];
  float hf = 0.f;
  float bsum[4];
#pragma unroll
  for (int g = 0; g < 4; ++g)
    bsum[g] = bih[layer * 2048 + g * 512 + j] + bhh[layer * 2048 + g * 512 + j];
  __syncthreads();

  const int br0 = ((ah * 2 + 0) << 4) + m;
  const int br1 = ((ah * 2 + 1) << 4) + m;
  const short* xo = (const short*)out;
  const int* f0p = flags + lane * 32;          // layer-0 flags, padded
  const int* f1p = flags + (64 + lane) * 32;   // layer-1 flags, padded

  f32x4 acc[2][2];

#define ZACC()                                                   \
  {                                                              \
    _Pragma("unroll") for (int u = 0; u < 2; ++u)                \
        _Pragma("unroll") for (int v = 0; v < 2; ++v)            \
            acc[u][v] = f32x4{0.f, 0.f, 0.f, 0.f};               \
  }

#define PA(rX, cc, br) \
  ((rX) + ((((cbase + (cc)) << 2) + koq) << 9) + (br) * 8)

#define HH_MFMA(Ah, Al)                                                        \
  _Pragma("unroll") for (int cc = 0; cc < 4; ++cc) {                           \
    const int c = cbase + cc;                                                  \
    short8 bh0 = *(const short8*)(lw + 16384 + (c * 2 + 0) * 512 + lane * 8);  \
    short8 bl0 = *(const short8*)(lw + 16384 + (c * 2 + 1) * 512 + lane * 8);  \
    short8 bh1 = *(const short8*)(lw + 16384 + ((16 + c) * 2 + 0) * 512 + lane * 8); \
    short8 bl1 = *(const short8*)(lw + 16384 + ((16 + c) * 2 + 1) * 512 + lane * 8); \
    _Pragma("unroll") for (int it = 0; it < 2; ++it) {                         \
      short8 a = Ah[cc * 2 + it];                                              \
      short8 al = Al[cc * 2 + it];                                             \
      acc[0][it] = __builtin_amdgcn_mfma_f32_16x16x32_bf16(a, bh0, acc[0][it], 0, 0, 0); \
      acc[0][it] = __builtin_amdgcn_mfma_f32_16x16x32_bf16(a, bl0, acc[0][it], 0, 0, 0); \
      acc[0][it] = __builtin_amdgcn_mfma_f32_16x16x32_bf16(al, bh0, acc[0][it], 0, 0, 0); \
      acc[1][it] = __builtin_amdgcn_mfma_f32_16x16x32_bf16(a, bh1, acc[1][it], 0, 0, 0); \
      acc[1][it] = __builtin_amdgcn_mfma_f32_16x16x32_bf16(a, bl1, acc[1][it], 0, 0, 0); \
      acc[1][it] = __builtin_amdgcn_mfma_f32_16x16x32_bf16(al, bh1, acc[1][it], 0, 0, 0); \
    }                                                                          \
  }

#define EPILOGUE(CN, HN)                                                       \
  _Pragma("unroll") for (int bt = 0; bt < 2; ++bt)                             \
      _Pragma("unroll") for (int it = 0; it < 2; ++it) {                       \
    const int srow = bt * 16 + m;                                              \
    const int col = ((ah * 2 + it) << 4) + (koq << 2);                         \
    _Pragma("unroll") for (int r = 0; r < 4; ++r)                              \
        sG[(kq * 32 + srow) * 66 + col + r] = acc[bt][it][r];                  \
  }                                                                            \
  __syncthreads();                                                             \
  float CN, HN;                                                                \
  {                                                                            \
    const int bt = sj >> 2, jl = sj & 3;                                       \
    float gv[4];                                                               \
    _Pragma("unroll") for (int g = 0; g < 4; ++g) {                            \
      const int s = bt * 16 + g * 4 + jl;                                      \
      gv[g] = sG[(0 * 32 + s) * 66 + sb] + sG[(1 * 32 + s) * 66 + sb] +        \
              sG[(2 * 32 + s) * 66 + sb] + sG[(3 * 32 + s) * 66 + sb] +        \
              bsum[g];                                                         \
    }                                                                          \
    CN = sigf(gv[1]) * creg + sigf(gv[0]) * tanh_(gv[2]);                      \
    HN = sigf(gv[3]) * tanh_(CN);                                              \
  }

  if (layer == 0) {
    // ---- LAYER 0: own flag chain; h0 ring depth 4; ring guard on fl1 ----
    ZACC();
#pragma unroll
    for (int cc = 0; cc < 4; ++cc) {  // prologue ih(0)
      const int c = cbase + cc;
      const int k = c * 32 + (koq << 3);
      short8 b0 = *(const short8*)(lw + c * 512 + lane * 8);
      short8 b1 = *(const short8*)(lw + (16 + c) * 512 + lane * 8);
#pragma unroll
      for (int it = 0; it < 2; ++it) {
        const int br = it ? br1 : br0;
        short8 a = *(const short8*)(xo + ((size_t)br * TT + 0) * 1024 + k);
        acc[0][it] = __builtin_amdgcn_mfma_f32_16x16x32_bf16(a, b0, acc[0][it], 0, 0, 0);
        acc[1][it] = __builtin_amdgcn_mfma_f32_16x16x32_bf16(a, b1, acc[1][it], 0, 0, 0);
      }
    }

    for (int p = 0; p < TT; ++p) {
      if (tid < 64) {  // wait: peers at p, ring guard fl1 >= p-3
        int f0, f1;
        for (;;) {
          pollld(f0, f1, f0p, f1p);
          if (__all(f0 >= p && f1 >= p - 3)) break;
          __builtin_amdgcn_s_sleep(1);
        }
      }
      __syncthreads();

      short8 Ah[8], Al[8];
      const short* rh = h0hi + ((p - 1) & 3) * 32768;
      const short* rl = h0lo + ((p - 1) & 3) * 32768;
      ld8_nw(Ah, PA(rh, 0, br0), PA(rh, 0, br1), PA(rh, 1, br0), PA(rh, 1, br1),
                 PA(rh, 2, br0), PA(rh, 2, br1), PA(rh, 3, br0), PA(rh, 3, br1));
      ld8_nw(Al, PA(rl, 0, br0), PA(rl, 0, br1), PA(rl, 1, br0), PA(rl, 1, br1),
                 PA(rl, 2, br0), PA(rl, 2, br1), PA(rl, 3, br0), PA(rl, 3, br1));
      TIE8(Ah, "s_waitcnt vmcnt(0)");
      TIE8(Al, "");
      HH_MFMA(Ah, Al);

      EPILOGUE(cn, hn);
      creg = cn;
      hf = hn;
      {
        short* dh = h0hi + (p & 3) * 32768 + (j8 << 9) + tid;
        short* dl = h0lo + (p & 3) * 32768 + (j8 << 9) + tid;
        const short hb = f2bf(hn);
        stc_short(dh, hb);
        stc_short(dl, f2bf(hn - bf2f(hb)));
      }
      drain_vm();       // each wave drains its own coherent stores
      __syncthreads();  // all waves drained
      if (tid == 0) stc_int(flags + j8 * 32, p + 1);

      if (p + 1 < TT) {  // ih(p+1) while peers catch up
        ZACC();
#pragma unroll
        for (int cc = 0; cc < 4; ++cc) {
          const int c = cbase + cc;
          const int k = c * 32 + (koq << 3);
          short8 b0 = *(const short8*)(lw + c * 512 + lane * 8);
          short8 b1 = *(const short8*)(lw + (16 + c) * 512 + lane * 8);
#pragma unroll
          for (int it = 0; it < 2; ++it) {
            const int br = it ? br1 : br0;
            short8 a = *(const short8*)(xo + ((size_t)br * TT + p + 1) * 1024 + k);
            acc[0][it] = __builtin_amdgcn_mfma_f32_16x16x32_bf16(a, b0, acc[0][it], 0, 0, 0);
            acc[1][it] = __builtin_amdgcn_mfma_f32_16x16x32_bf16(a, b1, acc[1][it], 0, 0, 0);
          }
        }
      }
    }
  } else {
    // ---- LAYER 1: consumes h0 ring; Ax pre-issued when f0seen allows ----
    int f0seen = 0;
    for (int tau = 1; tau <= TT; ++tau) {
      const int tl = tau - 1;

      if (f0seen < tau) {  // rare: layer-0 not known-ahead; wait on fl0
        if (tid < 64) {
          int f0, fx;
          for (;;) {
            pollld(f0, fx, f0p, f0p);
            if (__all(f0 >= tau)) break;
            __builtin_amdgcn_s_sleep(1);
          }
        }
        __syncthreads();
        f0seen = tau;
      }

      // Ax burst (h0(tau-1)) -- data known-committed, RT hides under poll
      ZACC();
      short8 Ax[8], Ah[8], Al[8];
      const short* ph = h0hi + (tl & 3) * 32768;
      ld8_nw(Ax, PA(ph, 0, br0), PA(ph, 0, br1), PA(ph, 1, br0), PA(ph, 1, br1),
                 PA(ph, 2, br0), PA(ph, 2, br1), PA(ph, 3, br0), PA(ph, 3, br1));

      // wait own-layer peers at tau-1; sample fl0 min for f0seen
      if (tid < 64) {
        int f1, f0;
        for (;;) {
          pollld(f1, f0, f1p, f0p);
          if (__all(f1 >= tau - 1)) break;
          __builtin_amdgcn_s_sleep(1);
        }
        if (lane == 0) {}  // keep f0 live
        int mn = wave_min(f0);
        if (lane == 0) *sf0 = mn;
      }
      __syncthreads();
      f0seen = *sf0;

      const short* rh = h1hi + (tau & 1) * 32768;  // h1(tau-2)
      const short* rl = h1lo + (tau & 1) * 32768;
      ld8_nw(Ah, PA(rh, 0, br0), PA(rh, 0, br1), PA(rh, 1, br0), PA(rh, 1, br1),
                 PA(rh, 2, br0), PA(rh, 2, br1), PA(rh, 3, br0), PA(rh, 3, br1));
      ld8_nw(Al, PA(rl, 0, br0), PA(rl, 0, br1), PA(rl, 1, br0), PA(rl, 1, br1),
                 PA(rl, 2, br0), PA(rl, 2, br1), PA(rl, 3, br0), PA(rl, 3, br1));
      TIE8(Ax, "s_waitcnt vmcnt(16)");  // Ax retired; Ah/Al in flight
#pragma unroll
      for (int cc = 0; cc < 4; ++cc) {
        const int c = cbase + cc;
        short8 b0 = *(const short8*)(lw + c * 512 + lane * 8);
        short8 b1 = *(const short8*)(lw + (16 + c) * 512 + lane * 8);
#pragma unroll
        for (int it = 0; it < 2; ++it) {
          short8 a = Ax[cc * 2 + it];
          acc[0][it] = __builtin_amdgcn_mfma_f32_16x16x32_bf16(a, b0, acc[0][it], 0, 0, 0);
          acc[1][it] = __builtin_amdgcn_mfma_f32_16x16x32_bf16(a, b1, acc[1][it], 0, 0, 0);
        }
      }
      TIE8(Ah, "s_waitcnt vmcnt(0)");
      TIE8(Al, "");
      HH_MFMA(Ah, Al);

      EPILOGUE(cn, hn);
      creg = cn;
      hf = hn;
      {
        short* dh = h1hi + ((tau + 1) & 1) * 32768 + (j8 << 9) + tid;
        short* dl = h1lo + ((tau + 1) & 1) * 32768 + (j8 << 9) + tid;
        const short hb = f2bf(hn);
        stc_short(dh, hb);
        stc_short(dl, f2bf(hn - bf2f(hb)));
      }
      drain_vm();
      __syncthreads();
      if (tid == 0) stc_int(flags + (64 + j8) * 32, tau);
      __builtin_nontemporal_store(hn, &out[((size_t)sb * 512 + tl) * 512 + j]);
    }
  }

  // finals from registers
  out[16777216 + layer * 32768 + sb * 512 + j] = hf;
  out[16777216 + 65536 + layer * 32768 + sb * 512 + j] = creg;
}

// ---- host ---------------------------------------------------------------

extern "C" void kernel_launch(void* const* d_in, const int* in_sizes, int n_in,
                              void* d_out, int out_size, void* d_ws,
                              size_t ws_size, hipStream_t stream) {
  const float* x = (const float*)d_in[0];
  const float* h0 = (const float*)d_in[1];
  const float* c0 = (const float*)d_in[2];
  const float* Wih = (const float*)d_in[3];
  const float* Whh = (const float*)d_in[4];
  const float* bih = (const float*)d_in[5];
  const float* bhh = (const float*)d_in[6];
  float* out = (float*)d_out;

  char* ws = (char*)d_ws;
  short* wp   = (short*)(ws + 0);              // 12 MB fragment-packed W
  short* h0hi = (short*)(ws + 12582912);       // 256 KB: 4-slot ring
  short* h0lo = (short*)(ws + 12845056);       // 256 KB
  short* h1hi = (short*)(ws + 13107200);       // 128 KB: 2-slot parity
  short* h1lo = (short*)(ws + 13238272);       // 128 KB
  int*  flags = (int*)(ws + 13369344);         // 16 KB: 128 padded lines
  // total ws use: ~12.9 MB (proven budget)

  hipFuncSetAttribute(reinterpret_cast<const void*>(lstm_persist),
                      hipFuncAttributeMaxDynamicSharedMemorySize, 132352);

  conv_x<<<8192, 256, 0, stream>>>(x, (short*)out);
  conv_w<<<3072, 256, 0, stream>>>(Wih, Whh, wp);
  init_state<<<256, 256, 0, stream>>>(h0, h0hi, h0lo, h1hi, h1lo, flags);

  void* args[] = {(void*)&wp,   (void*)&c0,   (void*)&bih,  (void*)&bhh,
                  (void*)&h0hi, (void*)&h0lo, (void*)&h1hi, (void*)&h1lo,
                  (void*)&flags, (void*)&out};
  hipLaunchCooperativeKernel(reinterpret_cast<void*>(lstm_persist), dim3(128),
                             dim3(512), args, 132352, stream);
}